// Round 1
// baseline (1631.201 us; speedup 1.0000x reference)
//
#include <hip/hip_runtime.h>

#define N_NODES 262144
#define MEM_DIM 512
#define MSG_DIM 1024
#define N_UPD   65536

typedef __attribute__((ext_vector_type(8)))  __bf16 bf16x8;
typedef __attribute__((ext_vector_type(16))) float  floatx16;
typedef __attribute__((ext_vector_type(4)))  unsigned short ushortx4;

static __device__ __forceinline__ unsigned short f2bf(float f) {
  unsigned int u = __float_as_uint(f);
  u += 0x7fffu + ((u >> 16) & 1u);      // round-to-nearest-even
  return (unsigned short)(u >> 16);
}

static __device__ __forceinline__ void async16(const void* g, void* l) {
  __builtin_amdgcn_global_load_lds(
      (const __attribute__((address_space(1))) unsigned int*)g,
      (__attribute__((address_space(3))) unsigned int*)l, 16, 0, 0);
}

// ---- fp32 -> bf16 convert (grid-stride) ----
__global__ void cvt_kernel(const float4* __restrict__ src,
                           ushortx4* __restrict__ dst, int n4) {
  int stride = gridDim.x * blockDim.x;
  for (int i = blockIdx.x * blockDim.x + threadIdx.x; i < n4; i += stride) {
    float4 v = src[i];
    ushortx4 o;
    o.x = f2bf(v.x); o.y = f2bf(v.y); o.z = f2bf(v.z); o.w = f2bf(v.w);
    dst[i] = o;
  }
}

// ---- gather h = memory[ids] and convert to bf16 (dense [N_UPD][512]) ----
__global__ void gather_cvt_kernel(const float* __restrict__ memory,
                                  const int* __restrict__ ids,
                                  ushortx4* __restrict__ dst) {
  int u = blockIdx.x * blockDim.x + threadIdx.x;   // exact: N_UPD*128
  int i = u >> 7, c4 = u & 127;
  int g = ids[i];
  const float4* row = (const float4*)(memory + (size_t)g * MEM_DIM);
  float4 v = row[c4];
  ushortx4 o;
  o.x = f2bf(v.x); o.y = f2bf(v.y); o.z = f2bf(v.z); o.w = f2bf(v.w);
  dst[u] = o;
}

// ---- bulk copy memory -> out_mem, last_update -> out_lu ----
__global__ void copy_kernel(const float4* __restrict__ mem,
                            const float4* __restrict__ lu,
                            float4* __restrict__ out_mem,
                            float4* __restrict__ out_lu) {
  const int NM4 = N_NODES * MEM_DIM / 4;   // 33554432
  const int NL4 = N_NODES / 4;             // 65536
  int stride = gridDim.x * blockDim.x;
  for (int i = blockIdx.x * blockDim.x + threadIdx.x; i < NM4 + NL4; i += stride) {
    if (i < NM4) out_mem[i] = mem[i];
    else         out_lu[i - NM4] = lu[i - NM4];
  }
}

// ---- fused dual-GEMM + GRU + scatter ----
// block: 256 thr (4 waves). tile: BM=128 rows x BH=64 h-cols.
// wave (wm,wn): 64 rows x 32 cols, 4 acc tiles {r, z, i_n, h_n} of 32x32.
// phase0: A=messages(K=1024) B=W_ih; phase1: A=h(K=512) B=W_hh.
// r/z accumulators shared across phases (i_r+h_r fused pre-sigmoid).
__global__ __launch_bounds__(256, 2)
void gru_kernel(const unsigned short* __restrict__ msgb,
                const unsigned short* __restrict__ hb,
                const unsigned short* __restrict__ wih,
                const unsigned short* __restrict__ whh,
                const float* __restrict__ b_ih, const float* __restrict__ b_hh,
                const float* __restrict__ memory,
                const int* __restrict__ ids,
                const float* __restrict__ ts,
                float* __restrict__ out_mem, float* __restrict__ out_lu) {
  __shared__ unsigned short sA[128 * 64];   // 16 KB
  __shared__ unsigned short sB[192 * 64];   // 24 KB (3 gate row-groups x 64)

  const int tid  = threadIdx.x;
  const int lane = tid & 63;
  const int w    = tid >> 6;
  const int wm   = w & 1, wn = w >> 1;
  const int hc   = blockIdx.x * 64;        // H-tile base (x fast => band L2/L3 reuse)
  const int m0   = blockIdx.y * 128;

  if (blockIdx.x == 0 && tid < 128) {      // fold in timestamp scatter
    int m = m0 + tid;
    out_lu[ids[m]] = ts[m];
  }

  floatx16 accR[2], accZ[2], accN[2][2];
#pragma unroll
  for (int t = 0; t < 2; ++t)
#pragma unroll
    for (int e = 0; e < 16; ++e) {
      accR[t][e] = 0.f; accZ[t][e] = 0.f;
      accN[0][t][e] = 0.f; accN[1][t][e] = 0.f;
    }

  const int srow = tid >> 3;            // staging row within 32-row round
  const int scol = (tid & 7) * 8;       // staging k-col (8 bf16 = 16B)
  const int lrow = lane & 31;
  const int lko  = (lane >> 5) * 8;     // frag k offset

#pragma unroll
  for (int phase = 0; phase < 2; ++phase) {
    const unsigned short* Ap = phase ? hb : msgb;
    const unsigned short* Bp = phase ? whh : wih;
    const int K = phase ? 512 : 1024;
    for (int k0 = 0; k0 < K; k0 += 64) {
      __syncthreads();
      // stage A: 128x64 bf16, 4 rounds of 32 rows
#pragma unroll
      for (int j = 0; j < 4; ++j) {
        const unsigned short* g = Ap + (size_t)(m0 + j * 32 + srow) * K + (k0 + scol);
        async16(g, (char*)sA + j * 4096 + w * 1024);
      }
      // stage B: 192x64 bf16 (gates r,z,n), 6 rounds
#pragma unroll
      for (int j = 0; j < 6; ++j) {
        int brr  = j * 32 + srow;            // 0..191
        int gate = brr >> 6;                 // 0..2
        int wr   = gate * 512 + hc + (brr & 63);
        const unsigned short* g = Bp + (size_t)wr * K + (k0 + scol);
        async16(g, (char*)sB + j * 4096 + w * 1024);
      }
      __syncthreads();
#pragma unroll
      for (int kk = 0; kk < 4; ++kk) {
        int ko = kk * 16 + lko;
        bf16x8 a0 = *(const bf16x8*)&sA[(wm * 64 + lrow) * 64 + ko];
        bf16x8 a1 = *(const bf16x8*)&sA[(wm * 64 + 32 + lrow) * 64 + ko];
        bf16x8 vr = *(const bf16x8*)&sB[(wn * 32 + lrow) * 64 + ko];
        bf16x8 vz = *(const bf16x8*)&sB[(64 + wn * 32 + lrow) * 64 + ko];
        bf16x8 vn = *(const bf16x8*)&sB[(128 + wn * 32 + lrow) * 64 + ko];
        accR[0] = __builtin_amdgcn_mfma_f32_32x32x16_bf16(a0, vr, accR[0], 0, 0, 0);
        accR[1] = __builtin_amdgcn_mfma_f32_32x32x16_bf16(a1, vr, accR[1], 0, 0, 0);
        accZ[0] = __builtin_amdgcn_mfma_f32_32x32x16_bf16(a0, vz, accZ[0], 0, 0, 0);
        accZ[1] = __builtin_amdgcn_mfma_f32_32x32x16_bf16(a1, vz, accZ[1], 0, 0, 0);
        accN[phase][0] = __builtin_amdgcn_mfma_f32_32x32x16_bf16(a0, vn, accN[phase][0], 0, 0, 0);
        accN[phase][1] = __builtin_amdgcn_mfma_f32_32x32x16_bf16(a1, vn, accN[phase][1], 0, 0, 0);
      }
    }
  }

  // epilogue: GRU gates + scatter to out_mem[ids[m]]
  const int col = hc + wn * 32 + lrow;
  const float biasR  = b_ih[col] + b_hh[col];
  const float biasZ  = b_ih[512 + col] + b_hh[512 + col];
  const float biasNi = b_ih[1024 + col];
  const float biasNh = b_hh[1024 + col];
#pragma unroll
  for (int t = 0; t < 2; ++t) {
#pragma unroll
    for (int r = 0; r < 16; ++r) {
      int rowin = (r & 3) + 8 * (r >> 2) + 4 * (lane >> 5);
      int m = m0 + wm * 64 + t * 32 + rowin;
      int g = ids[m];
      size_t off = (size_t)g * MEM_DIM + col;
      float h  = memory[off];
      float rr = __builtin_amdgcn_rcpf(1.f + __expf(-(accR[t][r] + biasR)));
      float zz = __builtin_amdgcn_rcpf(1.f + __expf(-(accZ[t][r] + biasZ)));
      float ni = accN[0][t][r] + biasNi;
      float hn = accN[1][t][r] + biasNh;
      float e  = __expf(2.f * (ni + rr * hn));
      float nn = 1.f - 2.f * __builtin_amdgcn_rcpf(e + 1.f);
      out_mem[off] = (1.f - zz) * nn + zz * h;
    }
  }
}

extern "C" void kernel_launch(void* const* d_in, const int* in_sizes, int n_in,
                              void* d_out, int out_size, void* d_ws, size_t ws_size,
                              hipStream_t stream) {
  const float* memory      = (const float*)d_in[0];
  const float* last_update = (const float*)d_in[1];
  const int*   node_ids    = (const int*)d_in[2];
  const float* messages    = (const float*)d_in[3];
  const float* timestamps  = (const float*)d_in[4];
  const float* W_ih        = (const float*)d_in[5];
  const float* W_hh        = (const float*)d_in[6];
  const float* b_ih        = (const float*)d_in[7];
  const float* b_hh        = (const float*)d_in[8];

  float* out_mem = (float*)d_out;
  float* out_lu  = out_mem + (size_t)N_NODES * MEM_DIM;

  // workspace layout (bytes): wih_bf16 @0 (3 MB), whh_bf16 @3145728 (1.5 MB),
  // msg_bf16 @4718592 (128 MB), h_bf16 @138936320 (64 MB) => ~197 MB total
  char* ws = (char*)d_ws;
  unsigned short* wihb = (unsigned short*)ws;
  unsigned short* whhb = (unsigned short*)(ws + 3145728);
  unsigned short* msgb = (unsigned short*)(ws + 4718592);
  unsigned short* hb   = (unsigned short*)(ws + 138936320);

  cvt_kernel<<<1536, 256, 0, stream>>>((const float4*)W_ih, (ushortx4*)wihb, 1536 * 1024 / 4);
  cvt_kernel<<<768, 256, 0, stream>>>((const float4*)W_hh, (ushortx4*)whhb, 1536 * 512 / 4);
  cvt_kernel<<<16384, 256, 0, stream>>>((const float4*)messages, (ushortx4*)msgb, (int)((size_t)N_UPD * MSG_DIM / 4));
  gather_cvt_kernel<<<32768, 256, 0, stream>>>(memory, node_ids, (ushortx4*)hb);
  copy_kernel<<<32768, 256, 0, stream>>>((const float4*)memory, (const float4*)last_update,
                                         (float4*)d_out, (float4*)out_lu);
  gru_kernel<<<dim3(8, 512), 256, 0, stream>>>(msgb, hb, wihb, whhb, b_ih, b_hh,
                                               memory, node_ids, timestamps, out_mem, out_lu);
}